// Round 6
// baseline (382.481 us; speedup 1.0000x reference)
//
#include <hip/hip_runtime.h>
#include <hip/hip_bf16.h>

// Problem constants (B=2,T=64,N=64,D_IN=512,HID=256,L=2,H=4,C=64)
#define BT_G   128
#define NND    64
#define D_IN_  512
#define HID_   256
#define NH     4
#define NCH    64
#define NROWS  8192
#define NEG_SLOPE_ 0.2f
#define LN_EPS_    1e-5f

typedef __hip_bfloat16 bf16;

__device__ __forceinline__ float toF(bf16 x) { return __bfloat162float(x); }

// Dtype-select load: f32 ? fp32[i] : bf16[i]. Condition is wave-uniform.
// (Inputs are fp32 per R4/R5 identical-error A/B; kept as insurance.)
__device__ __forceinline__ float ldSel(const void* p, int i, bool f32) {
    if (f32) return ((const float*)p)[i];
    return toF(((const bf16*)p)[i]);
}

// ---------------------------------------------------------------------------
// prep: (a) input-dtype probe via LOW half-word exponent (bits 7..14): for
// bf16-packed words that's the lo element's exponent (in-band ~always for
// N(0,1)); for fp32 it's random mantissa bits (~18% in-band).
// (b) mask layout classify: int32/fp32 (word decode) / bf16 / byte-bool.
__global__ void prep_kernel(const unsigned int* __restrict__ xw,
                            const unsigned int* __restrict__ mw,
                            int* __restrict__ mout, int* __restrict__ flag) {
    __shared__ int loSane, okInt, okF32, okB16, okByte;
    const int tid = threadIdx.x;
    if (tid == 0) { loSane = 0; okInt = 1; okF32 = 1; okB16 = 1; okByte = 1; }
    __syncthreads();
    {
        unsigned w = xw[tid];                 // 1 KB probe — safe either dtype
        unsigned elo = (w >> 7) & 0xFFu;
        int s = ((w & 0xFFFFu) == 0u) || (elo >= 0x60u && elo <= 0x8Eu);
        atomicAdd(&loSane, s);
    }
    int aI = 1, aF = 1, aB = 1, aC = 1;
    for (int i = tid; i < 2048; i += 256) {   // 8 KB probe — safe all layouts
        unsigned w = mw[i];
        aI &= (w <= 1u);
        aF &= (w == 0u || w == 0x3F800000u);
        unsigned lo = w & 0xFFFFu, hi = w >> 16;
        aB &= ((lo == 0u || lo == 0x3F80u) && (hi == 0u || hi == 0x3F80u));
        aC &= (((w | (w >> 8) | (w >> 16) | (w >> 24)) & 0xFEu) == 0u);
    }
    if (!aI) atomicAnd(&okInt, 0);
    if (!aF) atomicAnd(&okF32, 0);
    if (!aB) atomicAnd(&okB16, 0);
    if (!aC) atomicAnd(&okByte, 0);
    __syncthreads();
    const int layout = (okInt || okF32) ? 0 : (okB16 ? 2 : (okByte ? 3 : 0));
    for (int i = tid; i < NROWS; i += 256) {
        int v;
        if (layout == 2)      v = (((const unsigned short*)mw)[i] != 0);
        else if (layout == 3) v = (((const unsigned char*)mw)[i] != 0);
        else                  v = (mw[i] != 0u);
        mout[i] = v;
    }
    if (tid == 0) *flag = (loSane < 150) ? 1 : 0;   // 1 = fp32, 0 = bf16
}

// ---------------------------------------------------------------------------
// C[M,Nc] = A[M,K] @ W[wOff..][K,Nc] + bias[bOff..][Nc].  C is fp32.
// aTag: 0 = A follows dtype flag (harness input), 1 = A fp32 (ws/d_out).
__global__ __launch_bounds__(256) void gemm_bias_kernel(
    const void* A, int aTag, const void* W, int wOff,
    const void* bias, int bOff, const int* __restrict__ flag,
    float* __restrict__ C, int M, int K, int Nc)
{
    constexpr int BM = 64, BN = 64, BK = 32;
    __shared__ __align__(16) float As[BK][BM + 4];
    __shared__ __align__(16) float Bs[BK][BN];
    const bool wf = (*flag != 0);
    const bool af = aTag ? true : wf;
    const int tid = threadIdx.x;
    const int tx = tid & 15, ty = tid >> 4;
    const int m0 = blockIdx.y * BM, n0 = blockIdx.x * BN;
    float acc[4][4] = {};

    for (int k0 = 0; k0 < K; k0 += BK) {
        for (int gi = tid; gi < (BM * BK) / 4; gi += 256) {
            int r = gi >> 3;
            int c = (gi & 7) * 4;
            int base = (m0 + r) * K + k0 + c;
            As[c + 0][r] = ldSel(A, base + 0, af);
            As[c + 1][r] = ldSel(A, base + 1, af);
            As[c + 2][r] = ldSel(A, base + 2, af);
            As[c + 3][r] = ldSel(A, base + 3, af);
        }
        for (int gi = tid; gi < (BK * BN) / 4; gi += 256) {
            int r = gi >> 4;
            int c = (gi & 15) * 4;
            int base = wOff + (k0 + r) * Nc + n0 + c;
            Bs[r][c + 0] = ldSel(W, base + 0, wf);
            Bs[r][c + 1] = ldSel(W, base + 1, wf);
            Bs[r][c + 2] = ldSel(W, base + 2, wf);
            Bs[r][c + 3] = ldSel(W, base + 3, wf);
        }
        __syncthreads();
        #pragma unroll
        for (int k = 0; k < BK; ++k) {
            const float4 a4 = *(const float4*)&As[k][ty * 4];
            const float4 b4 = *(const float4*)&Bs[k][tx * 4];
            const float a[4] = {a4.x, a4.y, a4.z, a4.w};
            const float b[4] = {b4.x, b4.y, b4.z, b4.w};
            #pragma unroll
            for (int ii = 0; ii < 4; ++ii)
                #pragma unroll
                for (int jj = 0; jj < 4; ++jj)
                    acc[ii][jj] = fmaf(a[ii], b[jj], acc[ii][jj]);
        }
        __syncthreads();
    }

    float bv[4];
    #pragma unroll
    for (int jj = 0; jj < 4; ++jj)
        bv[jj] = ldSel(bias, bOff + n0 + tx * 4 + jj, wf);
    #pragma unroll
    for (int ii = 0; ii < 4; ++ii) {
        float4 o;
        o.x = acc[ii][0] + bv[0]; o.y = acc[ii][1] + bv[1];
        o.z = acc[ii][2] + bv[2]; o.w = acc[ii][3] + bv[3];
        *(float4*)&C[(size_t)(m0 + ty * 4 + ii) * Nc + n0 + tx * 4] = o;
    }
}

// ---------------------------------------------------------------------------
// GATv2 attention per (graph, head). g MAY ALIAS xr: each block stages its
// own xr slice into LDS (barrier) before writing, and blocks touch disjoint
// slices, so the aliasing is safe.
__global__ __launch_bounds__(256) void attn_kernel(
    const float* xl, const float* xr,
    const void* att, int attOff, const int* msk, const int* flag,
    float* g)
{
    __shared__ float xls[64][65];
    __shared__ float xrs[64][64];
    __shared__ float es[64][65];
    __shared__ float av[64];
    __shared__ int   ms[64];
    const int tid  = threadIdx.x;
    const int head = blockIdx.x, gr = blockIdx.y;
    const bool wf = (*flag != 0);
    const float* xlg = xl + (size_t)gr * NND * HID_ + head * NCH;
    const float* xrg = xr + (size_t)gr * NND * HID_ + head * NCH;

    for (int i = tid; i < 4096; i += 256) {
        int r = i >> 6, c = i & 63;
        xls[r][c] = xlg[r * HID_ + c];
        xrs[r][c] = xrg[r * HID_ + c];
    }
    if (tid < 64) {
        av[tid] = ldSel(att, attOff + head * NCH + tid, wf);
        ms[tid] = msk[gr * NND + tid];
    }
    __syncthreads();

    // e[i][j] = sum_c av[c] * lrelu(xr[i][c] + xl[j][c]); masked to -1e9
    {
        const int j  = tid & 63;
        const int i0 = (tid >> 6) * 16;
        float eacc[16];
        #pragma unroll
        for (int q = 0; q < 16; ++q) eacc[q] = 0.f;
        for (int c = 0; c < 64; ++c) {
            const float xlv = xls[j][c];
            const float a   = av[c];
            #pragma unroll
            for (int q = 0; q < 16; ++q) {
                float s = xrs[i0 + q][c] + xlv;
                eacc[q] = fmaf(a, (s > 0.f ? s : NEG_SLOPE_ * s), eacc[q]);
            }
        }
        const int mj = ms[j];
        #pragma unroll
        for (int q = 0; q < 16; ++q) {
            const int i = i0 + q;
            const bool allowed = (ms[i] && mj) || (i == j);
            es[i][j] = allowed ? eacc[q] : -1e9f;
        }
    }
    __syncthreads();

    // row softmax over j (diag always allowed -> denom > 0)
    if (tid < 64) {
        float mx = -1e30f;
        for (int j = 0; j < 64; ++j) mx = fmaxf(mx, es[tid][j]);
        float s = 0.f;
        for (int j = 0; j < 64; ++j) {
            float ev = __expf(es[tid][j] - mx);
            es[tid][j] = ev; s += ev;
        }
        const float inv = 1.f / s;
        for (int j = 0; j < 64; ++j) es[tid][j] *= inv;
    }
    __syncthreads();

    // out[i][c] = sum_j alpha[i][j] * xl[j][c]
    {
        const int c  = tid & 63;
        const int i0 = (tid >> 6) * 16;
        float oacc[16];
        #pragma unroll
        for (int q = 0; q < 16; ++q) oacc[q] = 0.f;
        for (int j = 0; j < 64; ++j) {
            const float xlv = xls[j][c];
            #pragma unroll
            for (int q = 0; q < 16; ++q)
                oacc[q] = fmaf(es[i0 + q][j], xlv, oacc[q]);
        }
        float* go = g + (size_t)gr * NND * HID_ + head * NCH + c;
        #pragma unroll
        for (int q = 0; q < 16; ++q)
            go[(size_t)(i0 + q) * HID_] = oacc[q];
    }
}

// ---------------------------------------------------------------------------
// g + out_bias -> ELU -> LayerNorm -> + residual -> zero unmasked nodes.
// res is fp32. In-place (res == hout) is safe: each element is read and
// written by the same thread with a data dependency between them.
__global__ __launch_bounds__(256) void epilogue_kernel(
    const float* __restrict__ g, const float* res,
    const void* ob, const void* lns, const void* lnb, int vOff,
    const int* __restrict__ msk, const int* __restrict__ flag,
    float* hout)
{
    const bool wf = (*flag != 0);
    const int lane = threadIdx.x & 63;
    const int wave = threadIdx.x >> 6;
    const int m = blockIdx.x * 4 + wave;
    const float* grow = g + (size_t)m * HID_;
    float v[4];
    float sum = 0.f;
    #pragma unroll
    for (int q = 0; q < 4; ++q) {
        const int c = q * 64 + lane;
        float x = grow[c] + ldSel(ob, vOff + c, wf);
        x = x > 0.f ? x : (__expf(x) - 1.f);   // ELU (alpha=1)
        v[q] = x; sum += x;
    }
    #pragma unroll
    for (int off = 1; off < 64; off <<= 1) sum += __shfl_xor(sum, off);
    const float mu = sum * (1.f / 256.f);
    float vs = 0.f;
    #pragma unroll
    for (int q = 0; q < 4; ++q) { const float d = v[q] - mu; vs += d * d; }
    #pragma unroll
    for (int off = 1; off < 64; off <<= 1) vs += __shfl_xor(vs, off);
    const float rstd = rsqrtf(vs * (1.f / 256.f) + LN_EPS_);
    const int mnode = msk[m];
    const float* rrow = res + (size_t)m * HID_;
    float* ho = hout + (size_t)m * HID_;
    #pragma unroll
    for (int q = 0; q < 4; ++q) {
        const int c = q * 64 + lane;
        float y = (v[q] - mu) * rstd * ldSel(lns, vOff + c, wf)
                + ldSel(lnb, vOff + c, wf);
        y += rrow[c];
        ho[c] = mnode ? y : 0.f;
    }
}

// ---------------------------------------------------------------------------
// d_out already holds fp32 h0 from the input GEMM. For keep graphs
// (#masked > 1) overwrite with fp32 h_final; else leave the h0 rows.
__global__ __launch_bounds__(256) void finalize_kernel(
    const float* __restrict__ h, const int* __restrict__ msk,
    float* __restrict__ out)
{
    const int gr = blockIdx.x;
    __shared__ int cnt;
    if (threadIdx.x == 0) cnt = 0;
    __syncthreads();
    if (threadIdx.x < 64 && msk[gr * NND + threadIdx.x]) atomicAdd(&cnt, 1);
    __syncthreads();
    if (cnt <= 1) return;
    const size_t base = (size_t)gr * NND * HID_;
    for (int i = threadIdx.x; i < (NND * HID_) / 4; i += 256)
        ((float4*)(out + base))[i] = ((const float4*)(h + base))[i];
}

// ---------------------------------------------------------------------------
extern "C" void kernel_launch(void* const* d_in, const int* in_sizes, int n_in,
                              void* d_out, int out_size, void* d_ws, size_t ws_size,
                              hipStream_t stream) {
    float* out = (float*)d_out;    // reference output dtype is float32

    // ws layout (24.04 MB): [mcan 32KB][flag][pad to 40960][h 8MB][xlb 8MB][xrb 8MB]
    int*   mcan = (int*)d_ws;
    int*   flag = mcan + NROWS;
    float* big  = (float*)((char*)d_ws + 40960);
    const size_t SZ = (size_t)NROWS * HID_;    // 2,097,152 floats = 8 MB
    float* h    = big;
    float* xlb  = big + SZ;
    float* xrb  = big + 2 * SZ;
    float* gb   = xrb;                         // aliased (safe — see attn_kernel)

    prep_kernel<<<1, 256, 0, stream>>>(
        (const unsigned int*)d_in[0], (const unsigned int*)d_in[1], mcan, flag);

    // d_out <- fp32( x @ W_in + b_in )   (K = 512); serves as h0 everywhere.
    gemm_bias_kernel<<<dim3(HID_ / 64, NROWS / 64), 256, 0, stream>>>(
        d_in[0], /*aTag=*/0, d_in[2], 0, d_in[3], 0, flag,
        out, NROWS, D_IN_, HID_);

    for (int li = 0; li < 2; ++li) {
        const float* src = (li == 0) ? out : h;
        const int wOff = li * HID_ * HID_;
        const int vOff = li * HID_;
        gemm_bias_kernel<<<dim3(HID_ / 64, NROWS / 64), 256, 0, stream>>>(
            src, /*aTag=*/1, d_in[4], wOff, d_in[5], vOff, flag,
            xlb, NROWS, HID_, HID_);
        gemm_bias_kernel<<<dim3(HID_ / 64, NROWS / 64), 256, 0, stream>>>(
            src, /*aTag=*/1, d_in[6], wOff, d_in[7], vOff, flag,
            xrb, NROWS, HID_, HID_);
        attn_kernel<<<dim3(NH, BT_G), 256, 0, stream>>>(
            xlb, xrb, d_in[8], li * NH * NCH, mcan, flag, gb);
        epilogue_kernel<<<NROWS / 4, 256, 0, stream>>>(
            gb, src, d_in[9], d_in[10], d_in[11], vOff, mcan, flag, h);
    }

    finalize_kernel<<<BT_G, 256, 0, stream>>>(h, mcan, out);

    (void)in_sizes; (void)n_in; (void)out_size; (void)ws_size;
}

// Round 7
// 227.578 us; speedup vs baseline: 1.6807x; 1.6807x over previous
//
#include <hip/hip_runtime.h>
#include <hip/hip_bf16.h>

// Problem constants (B=2,T=64,N=64,D_IN=512,HID=256,L=2,H=4,C=64)
#define BT_G   128
#define NND    64
#define D_IN_  512
#define HID_   256
#define NH     4
#define NCH    64
#define NROWS  8192
#define NEG_SLOPE_ 0.2f
#define LN_EPS_    1e-5f

typedef __hip_bfloat16 bf16;
typedef __attribute__((ext_vector_type(8))) short short8;   // 8 bf16 = 4 VGPRs
typedef __attribute__((ext_vector_type(4))) float float4v;  // MFMA C/D

__device__ __forceinline__ float toF(bf16 x) { return __bfloat162float(x); }

// ---------------------------------------------------------------------------
// prep: canonicalize person_mask (int32 / fp32 / bf16 / byte-bool layouts)
// into int 0/1. (Float inputs proven fp32 by R4/R5 identical-error A/B.)
__global__ void prep_kernel(const unsigned int* __restrict__ mw,
                            int* __restrict__ mout) {
    __shared__ int okInt, okF32, okB16, okByte;
    const int tid = threadIdx.x;
    if (tid == 0) { okInt = 1; okF32 = 1; okB16 = 1; okByte = 1; }
    __syncthreads();
    int aI = 1, aF = 1, aB = 1, aC = 1;
    for (int i = tid; i < 2048; i += 256) {   // 8 KB probe — safe all layouts
        unsigned w = mw[i];
        aI &= (w <= 1u);
        aF &= (w == 0u || w == 0x3F800000u);
        unsigned lo = w & 0xFFFFu, hi = w >> 16;
        aB &= ((lo == 0u || lo == 0x3F80u) && (hi == 0u || hi == 0x3F80u));
        aC &= (((w | (w >> 8) | (w >> 16) | (w >> 24)) & 0xFEu) == 0u);
    }
    if (!aI) atomicAnd(&okInt, 0);
    if (!aF) atomicAnd(&okF32, 0);
    if (!aB) atomicAnd(&okB16, 0);
    if (!aC) atomicAnd(&okByte, 0);
    __syncthreads();
    const int layout = (okInt || okF32) ? 0 : (okB16 ? 2 : (okByte ? 3 : 0));
    for (int i = tid; i < NROWS; i += 256) {
        int v;
        if (layout == 2)      v = (((const unsigned short*)mw)[i] != 0);
        else if (layout == 3) v = (((const unsigned char*)mw)[i] != 0);
        else                  v = (mw[i] != 0u);
        mout[i] = v;
    }
}

// ---------------------------------------------------------------------------
// fp32 -> bf16 elementwise (n multiple of 2048; 8 elems/thread, 16 B stores)
__global__ __launch_bounds__(256) void cvt_bf16_kernel(
    const float* __restrict__ in, bf16* __restrict__ out, int n) {
    const int i = (blockIdx.x * 256 + threadIdx.x) * 8;
    if (i >= n) return;
    const float4 a = *(const float4*)(in + i);
    const float4 b = *(const float4*)(in + i + 4);
    union { bf16 h[8]; float4 v; } u;
    u.h[0] = __float2bfloat16(a.x); u.h[1] = __float2bfloat16(a.y);
    u.h[2] = __float2bfloat16(a.z); u.h[3] = __float2bfloat16(a.w);
    u.h[4] = __float2bfloat16(b.x); u.h[5] = __float2bfloat16(b.y);
    u.h[6] = __float2bfloat16(b.z); u.h[7] = __float2bfloat16(b.w);
    *(float4*)(out + i) = u.v;
}

// ---------------------------------------------------------------------------
// out[b][c][r] = bf16(in[b][r][c]).  R,C multiples of 32. 256 thr = 32x8.
__global__ __launch_bounds__(256) void transpose_cvt_kernel(
    const float* __restrict__ in, bf16* __restrict__ out, int R, int C) {
    __shared__ float t[32][33];
    const size_t bo = (size_t)blockIdx.z * R * C;
    const int c0 = blockIdx.x * 32, r0 = blockIdx.y * 32;
    const int tx = threadIdx.x & 31, ty = threadIdx.x >> 5;
    #pragma unroll
    for (int i = 0; i < 4; ++i)
        t[ty + 8 * i][tx] = in[bo + (size_t)(r0 + ty + 8 * i) * C + c0 + tx];
    __syncthreads();
    #pragma unroll
    for (int i = 0; i < 4; ++i)
        out[bo + (size_t)(c0 + ty + 8 * i) * R + r0 + tx] =
            __float2bfloat16(t[tx][ty + 8 * i]);
}

// ---------------------------------------------------------------------------
// C[M][N] fp32 = A[M][K](bf16) @ BT[N][K](bf16)^T + bias[N](fp32).
// Optional bf16 copy of C into Cb (for next-stage A operand).
// Tile 64x64, BK=64, 4 waves in 2x2; wave tile 32x32 = 2x2 mfma 16x16x32.
// LDS rows padded to 72 bf16 -> frag b128 reads are 2-way (free).
__global__ __launch_bounds__(256) void gemm_mfma_kernel(
    const bf16* __restrict__ A, const bf16* __restrict__ BT,
    const float* __restrict__ bias, float* __restrict__ Cf,
    bf16* __restrict__ Cb, int M, int K, int N)
{
    __shared__ bf16 As[64 * 72];
    __shared__ bf16 Bs[64 * 72];
    const int tid  = threadIdx.x;
    const int wave = tid >> 6, lane = tid & 63;
    const int quad = lane >> 4, l16 = lane & 15;
    const int m0 = blockIdx.y * 64, n0 = blockIdx.x * 64;
    const int wm = (wave & 1) * 32, wn = (wave >> 1) * 32;

    float4v acc[2][2] = {};   // [mi][ni]

    const int r  = tid >> 2;            // 0..63: staging row
    const int kc = (tid & 3) * 16;      // 16 bf16 per thread per tile

    for (int k0 = 0; k0 < K; k0 += 64) {
        {
            const bf16* sa = A  + (size_t)(m0 + r) * K + k0 + kc;
            const bf16* sb = BT + (size_t)(n0 + r) * K + k0 + kc;
            const float4 a0 = *(const float4*)(sa);
            const float4 a1 = *(const float4*)(sa + 8);
            const float4 b0 = *(const float4*)(sb);
            const float4 b1 = *(const float4*)(sb + 8);
            *(float4*)(&As[r * 72 + kc])     = a0;
            *(float4*)(&As[r * 72 + kc + 8]) = a1;
            *(float4*)(&Bs[r * 72 + kc])     = b0;
            *(float4*)(&Bs[r * 72 + kc + 8]) = b1;
        }
        __syncthreads();
        #pragma unroll
        for (int kk = 0; kk < 64; kk += 32) {
            short8 af[2], bfr[2];
            #pragma unroll
            for (int mi = 0; mi < 2; ++mi)
                af[mi] = *(const short8*)(&As[(wm + mi * 16 + l16) * 72 + kk + quad * 8]);
            #pragma unroll
            for (int ni = 0; ni < 2; ++ni)
                bfr[ni] = *(const short8*)(&Bs[(wn + ni * 16 + l16) * 72 + kk + quad * 8]);
            #pragma unroll
            for (int mi = 0; mi < 2; ++mi)
                #pragma unroll
                for (int ni = 0; ni < 2; ++ni)
                    acc[mi][ni] = __builtin_amdgcn_mfma_f32_16x16x32_bf16(
                        af[mi], bfr[ni], acc[mi][ni], 0, 0, 0);
        }
        __syncthreads();
    }

    // C/D layout: col = l16, row = quad*4 + reg   [m89/m91-verified]
    #pragma unroll
    for (int mi = 0; mi < 2; ++mi) {
        #pragma unroll
        for (int ni = 0; ni < 2; ++ni) {
            const int col = n0 + wn + ni * 16 + l16;
            const float bv = bias[col];
            #pragma unroll
            for (int rr = 0; rr < 4; ++rr) {
                const int row = m0 + wm + mi * 16 + quad * 4 + rr;
                const float v = acc[mi][ni][rr] + bv;
                Cf[(size_t)row * N + col] = v;
                if (Cb) Cb[(size_t)row * N + col] = __float2bfloat16(v);
            }
        }
    }
}

// ---------------------------------------------------------------------------
// GATv2 attention per (graph, head). g MAY ALIAS xr (block stages its xr
// slice into LDS before writing; slices disjoint across blocks).
__global__ __launch_bounds__(256) void attn_kernel(
    const float* xl, const float* xr,
    const float* att, const int* msk, float* g)
{
    __shared__ float xls[64][65];
    __shared__ float xrs[64][64];
    __shared__ float es[64][65];
    __shared__ float av[64];
    __shared__ int   ms[64];
    const int tid  = threadIdx.x;
    const int head = blockIdx.x, gr = blockIdx.y;
    const float* xlg = xl + (size_t)gr * NND * HID_ + head * NCH;
    const float* xrg = xr + (size_t)gr * NND * HID_ + head * NCH;

    for (int i = tid; i < 4096; i += 256) {
        int rr = i >> 6, c = i & 63;
        xls[rr][c] = xlg[rr * HID_ + c];
        xrs[rr][c] = xrg[rr * HID_ + c];
    }
    if (tid < 64) {
        av[tid] = att[head * NCH + tid];
        ms[tid] = msk[gr * NND + tid];
    }
    __syncthreads();

    {
        const int j  = tid & 63;
        const int i0 = (tid >> 6) * 16;
        float eacc[16];
        #pragma unroll
        for (int q = 0; q < 16; ++q) eacc[q] = 0.f;
        for (int c = 0; c < 64; ++c) {
            const float xlv = xls[j][c];
            const float a   = av[c];
            #pragma unroll
            for (int q = 0; q < 16; ++q) {
                float s = xrs[i0 + q][c] + xlv;
                eacc[q] = fmaf(a, (s > 0.f ? s : NEG_SLOPE_ * s), eacc[q]);
            }
        }
        const int mj = ms[j];
        #pragma unroll
        for (int q = 0; q < 16; ++q) {
            const int i = i0 + q;
            const bool allowed = (ms[i] && mj) || (i == j);
            es[i][j] = allowed ? eacc[q] : -1e9f;
        }
    }
    __syncthreads();

    if (tid < 64) {
        float mx = -1e30f;
        for (int j = 0; j < 64; ++j) mx = fmaxf(mx, es[tid][j]);
        float s = 0.f;
        for (int j = 0; j < 64; ++j) {
            float ev = __expf(es[tid][j] - mx);
            es[tid][j] = ev; s += ev;
        }
        const float inv = 1.f / s;
        for (int j = 0; j < 64; ++j) es[tid][j] *= inv;
    }
    __syncthreads();

    {
        const int c  = tid & 63;
        const int i0 = (tid >> 6) * 16;
        float oacc[16];
        #pragma unroll
        for (int q = 0; q < 16; ++q) oacc[q] = 0.f;
        for (int j = 0; j < 64; ++j) {
            const float xlv = xls[j][c];
            #pragma unroll
            for (int q = 0; q < 16; ++q)
                oacc[q] = fmaf(es[i0 + q][j], xlv, oacc[q]);
        }
        float* go = g + (size_t)gr * NND * HID_ + head * NCH + c;
        #pragma unroll
        for (int q = 0; q < 16; ++q)
            go[(size_t)(i0 + q) * HID_] = oacc[q];
    }
}

// ---------------------------------------------------------------------------
// g + ob -> ELU -> LayerNorm -> + res -> zero unmasked. In-place res==hout
// safe (same-thread read-before-write). Optional bf16 copy into hb.
__global__ __launch_bounds__(256) void epilogue_kernel(
    const float* __restrict__ g, const float* res,
    const float* __restrict__ ob, const float* __restrict__ lns,
    const float* __restrict__ lnb, const int* __restrict__ msk,
    float* hout, bf16* hb)
{
    const int lane = threadIdx.x & 63;
    const int wave = threadIdx.x >> 6;
    const int m = blockIdx.x * 4 + wave;
    const float* grow = g + (size_t)m * HID_;
    float v[4];
    float sum = 0.f;
    #pragma unroll
    for (int q = 0; q < 4; ++q) {
        const int c = q * 64 + lane;
        float x = grow[c] + ob[c];
        x = x > 0.f ? x : (__expf(x) - 1.f);   // ELU (alpha=1)
        v[q] = x; sum += x;
    }
    #pragma unroll
    for (int off = 1; off < 64; off <<= 1) sum += __shfl_xor(sum, off);
    const float mu = sum * (1.f / 256.f);
    float vs = 0.f;
    #pragma unroll
    for (int q = 0; q < 4; ++q) { const float d = v[q] - mu; vs += d * d; }
    #pragma unroll
    for (int off = 1; off < 64; off <<= 1) vs += __shfl_xor(vs, off);
    const float rstd = rsqrtf(vs * (1.f / 256.f) + LN_EPS_);
    const int mnode = msk[m];
    const float* rrow = res + (size_t)m * HID_;
    float* ho = hout + (size_t)m * HID_;
    #pragma unroll
    for (int q = 0; q < 4; ++q) {
        const int c = q * 64 + lane;
        float y = (v[q] - mu) * rstd * lns[c] + lnb[c];
        y += rrow[c];
        y = mnode ? y : 0.f;
        ho[c] = y;
        if (hb) hb[(size_t)m * HID_ + c] = __float2bfloat16(y);
    }
}

// ---------------------------------------------------------------------------
// d_out holds fp32 h0. For keep graphs (#masked > 1) overwrite with h_final.
__global__ __launch_bounds__(256) void finalize_kernel(
    const float* __restrict__ h, const int* __restrict__ msk,
    float* __restrict__ out)
{
    const int gr = blockIdx.x;
    __shared__ int cnt;
    if (threadIdx.x == 0) cnt = 0;
    __syncthreads();
    if (threadIdx.x < 64 && msk[gr * NND + threadIdx.x]) atomicAdd(&cnt, 1);
    __syncthreads();
    if (cnt <= 1) return;
    const size_t base = (size_t)gr * NND * HID_;
    for (int i = threadIdx.x; i < (NND * HID_) / 4; i += 256)
        ((float4*)(out + base))[i] = ((const float4*)(h + base))[i];
}

// ---------------------------------------------------------------------------
extern "C" void kernel_launch(void* const* d_in, const int* in_sizes, int n_in,
                              void* d_out, int out_size, void* d_ws, size_t ws_size,
                              hipStream_t stream) {
    const float* x    = (const float*)d_in[0];
    const float* W_in = (const float*)d_in[2];
    const float* b_in = (const float*)d_in[3];
    const float* Wl   = (const float*)d_in[4];
    const float* bl   = (const float*)d_in[5];
    const float* Wr   = (const float*)d_in[6];
    const float* br   = (const float*)d_in[7];
    const float* att  = (const float*)d_in[8];
    const float* ob   = (const float*)d_in[9];
    const float* lns  = (const float*)d_in[10];
    const float* lnb  = (const float*)d_in[11];
    float* out = (float*)d_out;

    // ws layout (~36.8 MB):
    // [mcan 32K][h 8M][xlb 8M][xrb 8M][xb 8M][hxb 4M][WTin 256K][WlT 256K][WrT 256K]
    char* w = (char*)d_ws;
    int*   mcan = (int*)w;                      w += 32768;
    float* h    = (float*)w;                    w += (size_t)NROWS * HID_ * 4;
    float* xlb  = (float*)w;                    w += (size_t)NROWS * HID_ * 4;
    float* xrb  = (float*)w;                    w += (size_t)NROWS * HID_ * 4;
    bf16*  xb   = (bf16*)w;                     w += (size_t)NROWS * D_IN_ * 2;
    bf16*  hxb  = (bf16*)w;                     w += (size_t)NROWS * HID_ * 2;  // h0b then hb
    bf16*  WTin = (bf16*)w;                     w += (size_t)D_IN_ * HID_ * 2;
    bf16*  WlT  = (bf16*)w;                     w += (size_t)2 * HID_ * HID_ * 2;
    bf16*  WrT  = (bf16*)w;
    float* gb   = xrb;                          // aliased (safe — see attn_kernel)

    prep_kernel<<<1, 256, 0, stream>>>((const unsigned int*)d_in[1], mcan);

    // Input conversions: x -> bf16; W_in, Wl, Wr -> transposed bf16 [N][K].
    cvt_bf16_kernel<<<(NROWS * D_IN_) / 2048, 256, 0, stream>>>(x, xb, NROWS * D_IN_);
    transpose_cvt_kernel<<<dim3(HID_ / 32, D_IN_ / 32, 1), 256, 0, stream>>>(
        W_in, WTin, D_IN_, HID_);
    transpose_cvt_kernel<<<dim3(HID_ / 32, HID_ / 32, 2), 256, 0, stream>>>(
        Wl, WlT, HID_, HID_);
    transpose_cvt_kernel<<<dim3(HID_ / 32, HID_ / 32, 2), 256, 0, stream>>>(
        Wr, WrT, HID_, HID_);

    // d_out <- fp32 h0 = x @ W_in + b_in ; hxb <- bf16(h0)
    gemm_mfma_kernel<<<dim3(HID_ / 64, NROWS / 64), 256, 0, stream>>>(
        xb, WTin, b_in, out, hxb, NROWS, D_IN_, HID_);

    for (int li = 0; li < 2; ++li) {
        const float* resf = (li == 0) ? out : h;   // fp32 residual
        gemm_mfma_kernel<<<dim3(HID_ / 64, NROWS / 64), 256, 0, stream>>>(
            hxb, WlT + (size_t)li * HID_ * HID_, bl + li * HID_,
            xlb, (bf16*)nullptr, NROWS, HID_, HID_);
        gemm_mfma_kernel<<<dim3(HID_ / 64, NROWS / 64), 256, 0, stream>>>(
            hxb, WrT + (size_t)li * HID_ * HID_, br + li * HID_,
            xrb, (bf16*)nullptr, NROWS, HID_, HID_);
        attn_kernel<<<dim3(NH, BT_G), 256, 0, stream>>>(
            xlb, xrb, att + li * NH * NCH, mcan, gb);
        // epilogue: layer 0 writes h fp32 + hxb bf16 (layer-1 A operand);
        // layer 1 writes h fp32 only (in-place residual).
        epilogue_kernel<<<NROWS / 4, 256, 0, stream>>>(
            gb, resf, ob + li * HID_, lns + li * HID_, lnb + li * HID_,
            mcan, h, (li == 0) ? hxb : (bf16*)nullptr);
    }

    finalize_kernel<<<BT_G, 256, 0, stream>>>(h, mcan, out);

    (void)in_sizes; (void)n_in; (void)out_size; (void)ws_size;
}

// Round 8
// 213.452 us; speedup vs baseline: 1.7919x; 1.0662x over previous
//
#include <hip/hip_runtime.h>
#include <hip/hip_bf16.h>

// Problem constants (B=2,T=64,N=64,D_IN=512,HID=256,L=2,H=4,C=64)
#define BT_G   128
#define NND    64
#define D_IN_  512
#define HID_   256
#define NH     4
#define NCH    64
#define NROWS  8192
#define NEG_SLOPE_ 0.2f
#define LN_EPS_    1e-5f

typedef __hip_bfloat16 bf16;
typedef __attribute__((ext_vector_type(8))) short short8;   // 8 bf16 = 4 VGPRs
typedef __attribute__((ext_vector_type(4))) float float4v;  // MFMA C/D

__device__ __forceinline__ float toF(bf16 x) { return __bfloat162float(x); }

// ---------------------------------------------------------------------------
// prep: canonicalize person_mask (int32 / fp32 / bf16 / byte-bool layouts)
// into int 0/1.
__global__ void prep_kernel(const unsigned int* __restrict__ mw,
                            int* __restrict__ mout) {
    __shared__ int okInt, okF32, okB16, okByte;
    const int tid = threadIdx.x;
    if (tid == 0) { okInt = 1; okF32 = 1; okB16 = 1; okByte = 1; }
    __syncthreads();
    int aI = 1, aF = 1, aB = 1, aC = 1;
    for (int i = tid; i < 2048; i += 256) {   // 8 KB probe — safe all layouts
        unsigned w = mw[i];
        aI &= (w <= 1u);
        aF &= (w == 0u || w == 0x3F800000u);
        unsigned lo = w & 0xFFFFu, hi = w >> 16;
        aB &= ((lo == 0u || lo == 0x3F80u) && (hi == 0u || hi == 0x3F80u));
        aC &= (((w | (w >> 8) | (w >> 16) | (w >> 24)) & 0xFEu) == 0u);
    }
    if (!aI) atomicAnd(&okInt, 0);
    if (!aF) atomicAnd(&okF32, 0);
    if (!aB) atomicAnd(&okB16, 0);
    if (!aC) atomicAnd(&okByte, 0);
    __syncthreads();
    const int layout = (okInt || okF32) ? 0 : (okB16 ? 2 : (okByte ? 3 : 0));
    for (int i = tid; i < NROWS; i += 256) {
        int v;
        if (layout == 2)      v = (((const unsigned short*)mw)[i] != 0);
        else if (layout == 3) v = (((const unsigned char*)mw)[i] != 0);
        else                  v = (mw[i] != 0u);
        mout[i] = v;
    }
}

// ---------------------------------------------------------------------------
// fp32 -> bf16 elementwise (n multiple of 2048; 8 elems/thread)
__global__ __launch_bounds__(256) void cvt_bf16_kernel(
    const float* __restrict__ in, bf16* __restrict__ out, int n) {
    const int i = (blockIdx.x * 256 + threadIdx.x) * 8;
    if (i >= n) return;
    const float4 a = *(const float4*)(in + i);
    const float4 b = *(const float4*)(in + i + 4);
    union { bf16 h[8]; float4 v; } u;
    u.h[0] = __float2bfloat16(a.x); u.h[1] = __float2bfloat16(a.y);
    u.h[2] = __float2bfloat16(a.z); u.h[3] = __float2bfloat16(a.w);
    u.h[4] = __float2bfloat16(b.x); u.h[5] = __float2bfloat16(b.y);
    u.h[6] = __float2bfloat16(b.z); u.h[7] = __float2bfloat16(b.w);
    *(float4*)(out + i) = u.v;
}

// ---------------------------------------------------------------------------
// One launch transposes+converts all weights to bf16 [n][k] layouts.
// z=0: W_in(512x256)->WTin[256][512]; z=1,2: Wl[li](256x256)->WlrT[li][0:256];
// z=3,4: Wr[li]->WlrT[li][256:512]. All originals have 256 cols.
__global__ __launch_bounds__(256) void transpose_all_kernel(
    const float* __restrict__ W_in, const float* __restrict__ Wl,
    const float* __restrict__ Wr, bf16* __restrict__ WTin,
    bf16* __restrict__ WlrT) {
    __shared__ float t[32][33];
    const int z = blockIdx.z;
    const float* src; bf16* dst; int K;
    if (z == 0)      { src = W_in;                 dst = WTin;                          K = 512; }
    else if (z <= 2) { src = Wl + (z - 1) * 65536; dst = WlrT + (z - 1) * 131072;       K = 256; }
    else             { src = Wr + (z - 3) * 65536; dst = WlrT + (z - 3) * 131072 + 256 * 256; K = 256; }
    const int n0 = blockIdx.x * 32, k0 = blockIdx.y * 32;
    if (k0 >= K) return;
    const int tx = threadIdx.x & 31, ty = threadIdx.x >> 5;
    #pragma unroll
    for (int i = 0; i < 4; ++i)
        t[ty + 8 * i][tx] = src[(size_t)(k0 + ty + 8 * i) * 256 + n0 + tx];
    __syncthreads();
    #pragma unroll
    for (int i = 0; i < 4; ++i)
        dst[(size_t)(n0 + ty + 8 * i) * K + k0 + tx] =
            __float2bfloat16(t[tx][ty + 8 * i]);
}

// ---------------------------------------------------------------------------
// C[M][Ntot] = A[M][K](bf16) @ BT[Ntot][K]^T + bias.  Tile 128x64, BK=64.
// 4 waves 2x2; wave computes 64x32 via 4x2 mfma_f32_16x16x32_bf16.
// Output split: global col < 256 -> Ca[row*256+col] (+bias0), else
// Cbf[row*256+col-256] (+bias1). Both out buffers have row stride 256.
// Optional bf16 mirror Cb16 (only for the N=256 input GEMM).
__global__ __launch_bounds__(256) void gemm_mfma_kernel(
    const bf16* __restrict__ A, const bf16* __restrict__ BT,
    const float* __restrict__ bias0, const float* __restrict__ bias1,
    float* __restrict__ Ca, float* __restrict__ Cbf,
    bf16* __restrict__ Cb16, int M, int K)
{
    __shared__ bf16 As[128 * 72];   // +8 pad: frag b128 reads 2-way (free)
    __shared__ bf16 Bs[64 * 72];
    const int tid  = threadIdx.x;
    const int wave = tid >> 6, lane = tid & 63;
    const int quad = lane >> 4, l16 = lane & 15;
    const int m0 = blockIdx.y * 128, n0g = blockIdx.x * 64;
    const int wm = (wave & 1) * 64, wn = (wave >> 1) * 32;

    float4v acc[4][2] = {};
    const int r  = tid >> 2;          // 0..63
    const int cq = (tid & 3) * 16;    // 16 bf16 per quarter-row

    for (int k0 = 0; k0 < K; k0 += 64) {
        const bf16* sa0 = A  + (size_t)(m0 + r) * K + k0 + cq;
        const bf16* sa1 = sa0 + (size_t)64 * K;
        const bf16* sb  = BT + (size_t)(n0g + r) * K + k0 + cq;
        const float4 a00 = *(const float4*)(sa0);
        const float4 a01 = *(const float4*)(sa0 + 8);
        const float4 a10 = *(const float4*)(sa1);
        const float4 a11 = *(const float4*)(sa1 + 8);
        const float4 b0  = *(const float4*)(sb);
        const float4 b1  = *(const float4*)(sb + 8);
        __syncthreads();   // previous iter's LDS reads complete
        *(float4*)(&As[r * 72 + cq])            = a00;
        *(float4*)(&As[r * 72 + cq + 8])        = a01;
        *(float4*)(&As[(r + 64) * 72 + cq])     = a10;
        *(float4*)(&As[(r + 64) * 72 + cq + 8]) = a11;
        *(float4*)(&Bs[r * 72 + cq])            = b0;
        *(float4*)(&Bs[r * 72 + cq + 8])        = b1;
        __syncthreads();
        #pragma unroll
        for (int kk = 0; kk < 64; kk += 32) {
            short8 af[4], bf2[2];
            #pragma unroll
            for (int mi = 0; mi < 4; ++mi)
                af[mi] = *(const short8*)(&As[(wm + mi * 16 + l16) * 72 + kk + quad * 8]);
            #pragma unroll
            for (int ni = 0; ni < 2; ++ni)
                bf2[ni] = *(const short8*)(&Bs[(wn + ni * 16 + l16) * 72 + kk + quad * 8]);
            #pragma unroll
            for (int mi = 0; mi < 4; ++mi)
                #pragma unroll
                for (int ni = 0; ni < 2; ++ni)
                    acc[mi][ni] = __builtin_amdgcn_mfma_f32_16x16x32_bf16(
                        af[mi], bf2[ni], acc[mi][ni], 0, 0, 0);
        }
    }

    // C/D layout: col = l16, row = quad*4 + reg  [m89/m91-verified]
    const bool loHalf = (n0g < 256);
    float* Co = loHalf ? Ca : Cbf;
    const float* bp = loHalf ? bias0 : bias1;
    const int cbase = loHalf ? n0g : (n0g - 256);
    #pragma unroll
    for (int ni = 0; ni < 2; ++ni) {
        const int col = cbase + wn + ni * 16 + l16;
        const float bv = bp[col];
        #pragma unroll
        for (int mi = 0; mi < 4; ++mi) {
            #pragma unroll
            for (int rr = 0; rr < 4; ++rr) {
                const int row = m0 + wm + mi * 16 + quad * 4 + rr;
                const float v = acc[mi][ni][rr] + bv;
                Co[(size_t)row * 256 + col] = v;
                if (Cb16) Cb16[(size_t)row * 256 + col] = __float2bfloat16(v);
            }
        }
    }
}

// ---------------------------------------------------------------------------
// GATv2 attention per (graph, head). g MAY ALIAS xr (block stages its xr
// slice into LDS before writing; slices disjoint across blocks).
__global__ __launch_bounds__(256) void attn_kernel(
    const float* xl, const float* xr,
    const float* att, const int* msk, float* g)
{
    __shared__ float xls[64][65];
    __shared__ float xrs[64][64];
    __shared__ float es[64][65];
    __shared__ float av[64];
    __shared__ int   ms[64];
    const int tid  = threadIdx.x;
    const int head = blockIdx.x, gr = blockIdx.y;
    const float* xlg = xl + (size_t)gr * NND * HID_ + head * NCH;
    const float* xrg = xr + (size_t)gr * NND * HID_ + head * NCH;

    for (int i = tid; i < 4096; i += 256) {
        int rr = i >> 6, c = i & 63;
        xls[rr][c] = xlg[rr * HID_ + c];
        xrs[rr][c] = xrg[rr * HID_ + c];
    }
    if (tid < 64) {
        av[tid] = att[head * NCH + tid];
        ms[tid] = msk[gr * NND + tid];
    }
    __syncthreads();

    {
        const int j  = tid & 63;
        const int i0 = (tid >> 6) * 16;
        float eacc[16];
        #pragma unroll
        for (int q = 0; q < 16; ++q) eacc[q] = 0.f;
        for (int c = 0; c < 64; ++c) {
            const float xlv = xls[j][c];
            const float a   = av[c];
            #pragma unroll
            for (int q = 0; q < 16; ++q) {
                float s = xrs[i0 + q][c] + xlv;
                eacc[q] = fmaf(a, (s > 0.f ? s : NEG_SLOPE_ * s), eacc[q]);
            }
        }
        const int mj = ms[j];
        #pragma unroll
        for (int q = 0; q < 16; ++q) {
            const int i = i0 + q;
            const bool allowed = (ms[i] && mj) || (i == j);
            es[i][j] = allowed ? eacc[q] : -1e9f;
        }
    }
    __syncthreads();

    if (tid < 64) {
        float mx = -1e30f;
        for (int j = 0; j < 64; ++j) mx = fmaxf(mx, es[tid][j]);
        float s = 0.f;
        for (int j = 0; j < 64; ++j) {
            float ev = __expf(es[tid][j] - mx);
            es[tid][j] = ev; s += ev;
        }
        const float inv = 1.f / s;
        for (int j = 0; j < 64; ++j) es[tid][j] *= inv;
    }
    __syncthreads();

    {
        const int c  = tid & 63;
        const int i0 = (tid >> 6) * 16;
        float oacc[16];
        #pragma unroll
        for (int q = 0; q < 16; ++q) oacc[q] = 0.f;
        for (int j = 0; j < 64; ++j) {
            const float xlv = xls[j][c];
            #pragma unroll
            for (int q = 0; q < 16; ++q)
                oacc[q] = fmaf(es[i0 + q][j], xlv, oacc[q]);
        }
        float* go = g + (size_t)gr * NND * HID_ + head * NCH + c;
        #pragma unroll
        for (int q = 0; q < 16; ++q)
            go[(size_t)(i0 + q) * HID_] = oacc[q];
    }
}

// ---------------------------------------------------------------------------
// g + ob -> ELU -> LayerNorm -> + res -> zero unmasked.
// finalSel=0: write hout rows always (+ optional bf16 mirror hb).
// finalSel=1: hout is d_out holding h0; only overwrite rows of graphs with
// keep = (#masked nodes > 1), computed via ballot — fuses old finalize.
__global__ __launch_bounds__(256) void epilogue_kernel(
    const float* __restrict__ g, const float* res,
    const float* __restrict__ ob, const float* __restrict__ lns,
    const float* __restrict__ lnb, const int* __restrict__ msk,
    float* hout, bf16* hb, int finalSel)
{
    const int lane = threadIdx.x & 63;
    const int wave = threadIdx.x >> 6;
    const int m = blockIdx.x * 4 + wave;
    if (finalSel) {
        const int gr = m >> 6;
        const int mv = msk[gr * NND + lane];
        const unsigned long long bal = __ballot(mv != 0);
        if (__popcll(bal) <= 1) return;   // leave h0 rows in d_out
    }
    const float* grow = g + (size_t)m * HID_;
    float v[4];
    float sum = 0.f;
    #pragma unroll
    for (int q = 0; q < 4; ++q) {
        const int c = q * 64 + lane;
        float x = grow[c] + ob[c];
        x = x > 0.f ? x : (__expf(x) - 1.f);   // ELU (alpha=1)
        v[q] = x; sum += x;
    }
    #pragma unroll
    for (int off = 1; off < 64; off <<= 1) sum += __shfl_xor(sum, off);
    const float mu = sum * (1.f / 256.f);
    float vs = 0.f;
    #pragma unroll
    for (int q = 0; q < 4; ++q) { const float d = v[q] - mu; vs += d * d; }
    #pragma unroll
    for (int off = 1; off < 64; off <<= 1) vs += __shfl_xor(vs, off);
    const float rstd = rsqrtf(vs * (1.f / 256.f) + LN_EPS_);
    const int mnode = msk[m];
    const float* rrow = res + (size_t)m * HID_;
    float* ho = hout + (size_t)m * HID_;
    #pragma unroll
    for (int q = 0; q < 4; ++q) {
        const int c = q * 64 + lane;
        float y = (v[q] - mu) * rstd * lns[c] + lnb[c];
        y += rrow[c];
        y = mnode ? y : 0.f;
        ho[c] = y;
        if (hb) hb[(size_t)m * HID_ + c] = __float2bfloat16(y);
    }
}

// ---------------------------------------------------------------------------
extern "C" void kernel_launch(void* const* d_in, const int* in_sizes, int n_in,
                              void* d_out, int out_size, void* d_ws, size_t ws_size,
                              hipStream_t stream) {
    const float* x    = (const float*)d_in[0];
    const float* W_in = (const float*)d_in[2];
    const float* b_in = (const float*)d_in[3];
    const float* Wl   = (const float*)d_in[4];
    const float* bl   = (const float*)d_in[5];
    const float* Wr   = (const float*)d_in[6];
    const float* br   = (const float*)d_in[7];
    const float* att  = (const float*)d_in[8];
    const float* ob   = (const float*)d_in[9];
    const float* lns  = (const float*)d_in[10];
    const float* lnb  = (const float*)d_in[11];
    float* out = (float*)d_out;

    // ws (~37 MB): [mcan 32K][h 8M][xlb 8M][xrb 8M][xb 8M][hxb 4M][WTin 256K][WlrT 512K]
    char* w = (char*)d_ws;
    int*   mcan = (int*)w;                      w += 32768;
    float* h    = (float*)w;                    w += (size_t)NROWS * HID_ * 4;
    float* xlb  = (float*)w;                    w += (size_t)NROWS * HID_ * 4;
    float* xrb  = (float*)w;                    w += (size_t)NROWS * HID_ * 4;
    bf16*  xb   = (bf16*)w;                     w += (size_t)NROWS * D_IN_ * 2;
    bf16*  hxb  = (bf16*)w;                     w += (size_t)NROWS * HID_ * 2;
    bf16*  WTin = (bf16*)w;                     w += (size_t)D_IN_ * HID_ * 2;
    bf16*  WlrT = (bf16*)w;                     // [L][512][256]
    float* gb   = xrb;                          // aliased (safe — see attn_kernel)

    prep_kernel<<<1, 256, 0, stream>>>((const unsigned int*)d_in[1], mcan);
    cvt_bf16_kernel<<<(NROWS * D_IN_) / 2048, 256, 0, stream>>>(x, xb, NROWS * D_IN_);
    transpose_all_kernel<<<dim3(8, 16, 5), 256, 0, stream>>>(
        W_in, Wl, Wr, WTin, WlrT);

    // d_out <- fp32 h0 = x @ W_in + b_in ; hxb <- bf16(h0)
    gemm_mfma_kernel<<<dim3(HID_ / 64, NROWS / 128), 256, 0, stream>>>(
        xb, WTin, b_in, (const float*)nullptr, out, (float*)nullptr, hxb,
        NROWS, D_IN_);

    for (int li = 0; li < 2; ++li) {
        const float* resf = (li == 0) ? out : h;   // fp32 residual
        // fused xl|xr GEMM: N=512 over concatenated Wl^T|Wr^T
        gemm_mfma_kernel<<<dim3(512 / 64, NROWS / 128), 256, 0, stream>>>(
            hxb, WlrT + (size_t)li * 512 * HID_, bl + li * HID_, br + li * HID_,
            xlb, xrb, (bf16*)nullptr, NROWS, HID_);
        attn_kernel<<<dim3(NH, BT_G), 256, 0, stream>>>(
            xlb, xrb, att + li * NH * NCH, mcan, gb);
        if (li == 0) {
            epilogue_kernel<<<NROWS / 4, 256, 0, stream>>>(
                gb, resf, ob, lns, lnb, mcan, h, hxb, 0);
        } else {
            epilogue_kernel<<<NROWS / 4, 256, 0, stream>>>(
                gb, resf, ob + HID_, lns + HID_, lnb + HID_, mcan,
                out, (bf16*)nullptr, 1);
        }
    }

    (void)in_sizes; (void)n_in; (void)out_size; (void)ws_size;
}

// Round 9
// 176.819 us; speedup vs baseline: 2.1631x; 1.2072x over previous
//
#include <hip/hip_runtime.h>
#include <hip/hip_bf16.h>

// Problem constants (B=2,T=64,N=64,D_IN=512,HID=256,L=2,H=4,C=64)
#define BT_G   128
#define NND    64
#define D_IN_  512
#define HID_   256
#define NH     4
#define NCH    64
#define NROWS  8192
#define LN_EPS_    1e-5f

typedef __hip_bfloat16 bf16;
typedef __attribute__((ext_vector_type(8))) short short8;   // 8 bf16 = 4 VGPRs
typedef __attribute__((ext_vector_type(4))) float float4v;  // MFMA C/D

__device__ __forceinline__ float toF(bf16 x) { return __bfloat162float(x); }

// ---------------------------------------------------------------------------
// z=0: W_in(512x256)->WTin[256][512]; z=1,2: Wl[li]->WlrT[li][0:256][256];
// z=3,4: Wr[li]->WlrT[li][256:512][256]; z=5 (block 0,0): mask canonicalize.
__global__ __launch_bounds__(256) void transpose_all_kernel(
    const float* __restrict__ W_in, const float* __restrict__ Wl,
    const float* __restrict__ Wr, const unsigned int* __restrict__ mw,
    bf16* __restrict__ WTin, bf16* __restrict__ WlrT, int* __restrict__ mout) {
    const int z = blockIdx.z;
    const int tid = threadIdx.x;
    if (z == 5) {
        if (blockIdx.x || blockIdx.y) return;
        __shared__ int okInt, okF32, okB16, okByte;
        if (tid == 0) { okInt = 1; okF32 = 1; okB16 = 1; okByte = 1; }
        __syncthreads();
        int aI = 1, aF = 1, aB = 1, aC = 1;
        for (int i = tid; i < 2048; i += 256) {   // 8 KB probe — safe all layouts
            unsigned w = mw[i];
            aI &= (w <= 1u);
            aF &= (w == 0u || w == 0x3F800000u);
            unsigned lo = w & 0xFFFFu, hi = w >> 16;
            aB &= ((lo == 0u || lo == 0x3F80u) && (hi == 0u || hi == 0x3F80u));
            aC &= (((w | (w >> 8) | (w >> 16) | (w >> 24)) & 0xFEu) == 0u);
        }
        if (!aI) atomicAnd(&okInt, 0);
        if (!aF) atomicAnd(&okF32, 0);
        if (!aB) atomicAnd(&okB16, 0);
        if (!aC) atomicAnd(&okByte, 0);
        __syncthreads();
        const int layout = (okInt || okF32) ? 0 : (okB16 ? 2 : (okByte ? 3 : 0));
        for (int i = tid; i < NROWS; i += 256) {
            int v;
            if (layout == 2)      v = (((const unsigned short*)mw)[i] != 0);
            else if (layout == 3) v = (((const unsigned char*)mw)[i] != 0);
            else                  v = (mw[i] != 0u);
            mout[i] = v;
        }
        return;
    }
    __shared__ float t[32][33];
    const float* src; bf16* dst; int K;
    if (z == 0)      { src = W_in;                 dst = WTin;                    K = 512; }
    else if (z <= 2) { src = Wl + (z - 1) * 65536; dst = WlrT + (z - 1) * 131072; K = 256; }
    else             { src = Wr + (z - 3) * 65536; dst = WlrT + (z - 3) * 131072 + 256 * 256; K = 256; }
    const int n0 = blockIdx.x * 32, k0 = blockIdx.y * 32;
    if (k0 >= K) return;
    const int tx = tid & 31, ty = tid >> 5;
    #pragma unroll
    for (int i = 0; i < 4; ++i)
        t[ty + 8 * i][tx] = src[(size_t)(k0 + ty + 8 * i) * 256 + n0 + tx];
    __syncthreads();
    #pragma unroll
    for (int i = 0; i < 4; ++i)
        dst[(size_t)(n0 + ty + 8 * i) * K + k0 + tx] =
            __float2bfloat16(t[tx][ty + 8 * i]);
}

// ---------------------------------------------------------------------------
// Input GEMM: C[8192][256] = A_fp32[8192][512] @ WTin[256][512]^T + bias.
// Converts A to bf16 in-register during staging. Tile 64x64, BK=64,
// 4 waves 2x2 (each 32x32 via 2x2 mfma). Writes fp32 Cf + bf16 Cb16.
__global__ __launch_bounds__(256) void gemm_in_kernel(
    const float* __restrict__ A, const bf16* __restrict__ BT,
    const float* __restrict__ bias, float* __restrict__ Cf,
    bf16* __restrict__ Cb16)
{
    __shared__ bf16 As[64 * 72];
    __shared__ bf16 Bs[64 * 72];
    const int tid  = threadIdx.x;
    const int wave = tid >> 6, lane = tid & 63;
    const int quad = lane >> 4, l16 = lane & 15;
    const int m0 = blockIdx.y * 64, n0 = blockIdx.x * 64;
    const int wm = (wave & 1) * 32, wn = (wave >> 1) * 32;
    float4v acc[2][2] = {};
    const int r  = tid >> 2;
    const int cq = (tid & 3) * 16;

    for (int k0 = 0; k0 < D_IN_; k0 += 64) {
        const float* sa = A + (size_t)(m0 + r) * D_IN_ + k0 + cq;
        const float4 f0 = *(const float4*)(sa);
        const float4 f1 = *(const float4*)(sa + 4);
        const float4 f2 = *(const float4*)(sa + 8);
        const float4 f3 = *(const float4*)(sa + 12);
        const bf16* sb = BT + (size_t)(n0 + r) * D_IN_ + k0 + cq;
        const float4 b0 = *(const float4*)(sb);
        const float4 b1 = *(const float4*)(sb + 8);
        union { bf16 h[16]; float4 v[2]; } u;
        u.h[0]=__float2bfloat16(f0.x); u.h[1]=__float2bfloat16(f0.y);
        u.h[2]=__float2bfloat16(f0.z); u.h[3]=__float2bfloat16(f0.w);
        u.h[4]=__float2bfloat16(f1.x); u.h[5]=__float2bfloat16(f1.y);
        u.h[6]=__float2bfloat16(f1.z); u.h[7]=__float2bfloat16(f1.w);
        u.h[8]=__float2bfloat16(f2.x); u.h[9]=__float2bfloat16(f2.y);
        u.h[10]=__float2bfloat16(f2.z); u.h[11]=__float2bfloat16(f2.w);
        u.h[12]=__float2bfloat16(f3.x); u.h[13]=__float2bfloat16(f3.y);
        u.h[14]=__float2bfloat16(f3.z); u.h[15]=__float2bfloat16(f3.w);
        __syncthreads();
        *(float4*)(&As[r * 72 + cq])     = u.v[0];
        *(float4*)(&As[r * 72 + cq + 8]) = u.v[1];
        *(float4*)(&Bs[r * 72 + cq])     = b0;
        *(float4*)(&Bs[r * 72 + cq + 8]) = b1;
        __syncthreads();
        #pragma unroll
        for (int kk = 0; kk < 64; kk += 32) {
            short8 af[2], bf2[2];
            #pragma unroll
            for (int mi = 0; mi < 2; ++mi)
                af[mi] = *(const short8*)(&As[(wm + mi * 16 + l16) * 72 + kk + quad * 8]);
            #pragma unroll
            for (int ni = 0; ni < 2; ++ni)
                bf2[ni] = *(const short8*)(&Bs[(wn + ni * 16 + l16) * 72 + kk + quad * 8]);
            #pragma unroll
            for (int mi = 0; mi < 2; ++mi)
                #pragma unroll
                for (int ni = 0; ni < 2; ++ni)
                    acc[mi][ni] = __builtin_amdgcn_mfma_f32_16x16x32_bf16(
                        af[mi], bf2[ni], acc[mi][ni], 0, 0, 0);
        }
    }
    #pragma unroll
    for (int ni = 0; ni < 2; ++ni) {
        const int col = n0 + wn + ni * 16 + l16;
        const float bv = bias[col];
        #pragma unroll
        for (int mi = 0; mi < 2; ++mi)
            #pragma unroll
            for (int rr = 0; rr < 4; ++rr) {
                const int row = m0 + wm + mi * 16 + quad * 4 + rr;
                const float v = acc[mi][ni][rr] + bv;
                Cf[(size_t)row * HID_ + col] = v;
                Cb16[(size_t)row * HID_ + col] = __float2bfloat16(v);
            }
    }
}

// ---------------------------------------------------------------------------
// Fused xl|xr GEMM: C[M][512] = A[M][256](bf16) @ BT[512][256]^T + bias.
// Tile 128x64, BK=64; 4 waves 2x2, wave = 64x32 via 4x2 MFMA.
// col<256 -> Ca (+bias0) else Cbf (+bias1); both row-stride 256.
__global__ __launch_bounds__(256) void gemm_mfma_kernel(
    const bf16* __restrict__ A, const bf16* __restrict__ BT,
    const float* __restrict__ bias0, const float* __restrict__ bias1,
    float* __restrict__ Ca, float* __restrict__ Cbf, int M, int K)
{
    __shared__ bf16 As[128 * 72];
    __shared__ bf16 Bs[64 * 72];
    const int tid  = threadIdx.x;
    const int wave = tid >> 6, lane = tid & 63;
    const int quad = lane >> 4, l16 = lane & 15;
    const int m0 = blockIdx.y * 128, n0g = blockIdx.x * 64;
    const int wm = (wave & 1) * 64, wn = (wave >> 1) * 32;
    float4v acc[4][2] = {};
    const int r  = tid >> 2;
    const int cq = (tid & 3) * 16;

    for (int k0 = 0; k0 < K; k0 += 64) {
        const bf16* sa0 = A  + (size_t)(m0 + r) * K + k0 + cq;
        const bf16* sa1 = sa0 + (size_t)64 * K;
        const bf16* sb  = BT + (size_t)(n0g + r) * K + k0 + cq;
        const float4 a00 = *(const float4*)(sa0);
        const float4 a01 = *(const float4*)(sa0 + 8);
        const float4 a10 = *(const float4*)(sa1);
        const float4 a11 = *(const float4*)(sa1 + 8);
        const float4 b0  = *(const float4*)(sb);
        const float4 b1  = *(const float4*)(sb + 8);
        __syncthreads();
        *(float4*)(&As[r * 72 + cq])            = a00;
        *(float4*)(&As[r * 72 + cq + 8])        = a01;
        *(float4*)(&As[(r + 64) * 72 + cq])     = a10;
        *(float4*)(&As[(r + 64) * 72 + cq + 8]) = a11;
        *(float4*)(&Bs[r * 72 + cq])            = b0;
        *(float4*)(&Bs[r * 72 + cq + 8])        = b1;
        __syncthreads();
        #pragma unroll
        for (int kk = 0; kk < 64; kk += 32) {
            short8 af[4], bf2[2];
            #pragma unroll
            for (int mi = 0; mi < 4; ++mi)
                af[mi] = *(const short8*)(&As[(wm + mi * 16 + l16) * 72 + kk + quad * 8]);
            #pragma unroll
            for (int ni = 0; ni < 2; ++ni)
                bf2[ni] = *(const short8*)(&Bs[(wn + ni * 16 + l16) * 72 + kk + quad * 8]);
            #pragma unroll
            for (int mi = 0; mi < 4; ++mi)
                #pragma unroll
                for (int ni = 0; ni < 2; ++ni)
                    acc[mi][ni] = __builtin_amdgcn_mfma_f32_16x16x32_bf16(
                        af[mi], bf2[ni], acc[mi][ni], 0, 0, 0);
        }
    }
    const bool loHalf = (n0g < 256);
    float* Co = loHalf ? Ca : Cbf;
    const float* bp = loHalf ? bias0 : bias1;
    const int cbase = loHalf ? n0g : (n0g - 256);
    #pragma unroll
    for (int ni = 0; ni < 2; ++ni) {
        const int col = cbase + wn + ni * 16 + l16;
        const float bv = bp[col];
        #pragma unroll
        for (int mi = 0; mi < 4; ++mi)
            #pragma unroll
            for (int rr = 0; rr < 4; ++rr) {
                const int row = m0 + wm + mi * 16 + quad * 4 + rr;
                Co[(size_t)row * 256 + col] = acc[mi][ni][rr] + bv;
            }
    }
}

// ---------------------------------------------------------------------------
// GATv2 attention per (graph, head), 4x4-tiled, b128 LDS reads.
// lrelu(s) = 0.6s + 0.4|s|  ->  e = 0.6(P_i + Q_j) + 0.4 * sum_c a_c|s|,
// P_i = sum a_c xr_ic, Q_j = sum a_c xl_jc. Softmax 1/sum folded into the
// output scale. g MAY ALIAS xr (xr fully staged before writes; slices
// disjoint across blocks).
__global__ __launch_bounds__(256) void attn_kernel(
    const float* xl, const float* xr, const float* att,
    const int* msk, float* g)
{
    __shared__ float xls [64][68];   // xl row-major [j][c]   (phase 3)
    __shared__ float xlsT[64][68];   // [c][j]                (phase 1)
    __shared__ float xrsT[64][68];   // [c][i]                (phase 1)
    __shared__ float esT [64][68];   // [j][i]
    __shared__ float av[64], P[64], Q[64], mxf[64], inv[64];
    __shared__ float pmax[4][64], psum[4][64];
    __shared__ int   ms[64];
    const int tid  = threadIdx.x;
    const int head = blockIdx.x, gr = blockIdx.y;
    const int ti = tid >> 4, tj = tid & 15;       // 16x16 thread grid
    const int i0 = ti * 4, j0 = tj * 4;           // 4x4 tile
    const float* xlg = xl + (size_t)gr * NND * HID_ + head * NCH;
    const float* xrg = xr + (size_t)gr * NND * HID_ + head * NCH;

    // ---- staging: 16 elems/thread of xl (both layouts) and xr (transposed)
    {
        const int r  = tid >> 2;
        const int c0 = (tid & 3) * 16;
        float a[4][4], b[4][4];
        #pragma unroll
        for (int k = 0; k < 4; ++k) {
            *(float4*)a[k] = *(const float4*)(xlg + r * HID_ + c0 + 4 * k);
            *(float4*)b[k] = *(const float4*)(xrg + r * HID_ + c0 + 4 * k);
        }
        #pragma unroll
        for (int k = 0; k < 4; ++k)
            *(float4*)&xls[r][c0 + 4 * k] = *(float4*)a[k];
        #pragma unroll
        for (int k = 0; k < 4; ++k)
            #pragma unroll
            for (int w = 0; w < 4; ++w) {
                xlsT[c0 + 4 * k + w][r] = a[k][w];
                xrsT[c0 + 4 * k + w][r] = b[k][w];
            }
    }
    if (tid < 64) {
        av[tid] = att[head * NCH + tid];
        ms[tid] = msk[gr * NND + tid];
    }
    __syncthreads();

    // ---- phase 1: abs-sum accumulation, 2 x b128 per c
    float aa[4][4] = {};
    for (int c = 0; c < 64; ++c) {
        float xr4[4], xl4[4];
        *(float4*)xr4 = *(const float4*)&xrsT[c][i0];
        *(float4*)xl4 = *(const float4*)&xlsT[c][j0];
        const float a = av[c];
        #pragma unroll
        for (int y = 0; y < 4; ++y)
            #pragma unroll
            for (int x = 0; x < 4; ++x)
                aa[y][x] = fmaf(a, fabsf(xr4[y] + xl4[x]), aa[y][x]);
    }
    // P/Q by waves 0 and 1 (xlsT/xrsT stable since staging barrier)
    if (tid < 64) {
        float s = 0.f;
        for (int c = 0; c < 64; ++c) s = fmaf(av[c], xrsT[c][tid], s);
        P[tid] = s;
    } else if (tid < 128) {
        const int j = tid - 64;
        float s = 0.f;
        for (int c = 0; c < 64; ++c) s = fmaf(av[c], xlsT[c][j], s);
        Q[j] = s;
    }
    __syncthreads();

    // ---- combine, mask, write esT[j][i]
    {
        float Pv[4], Qv[4]; int mi4[4], mj4[4];
        #pragma unroll
        for (int y = 0; y < 4; ++y) { Pv[y] = P[i0 + y]; mi4[y] = ms[i0 + y]; }
        #pragma unroll
        for (int x = 0; x < 4; ++x) { Qv[x] = Q[j0 + x]; mj4[x] = ms[j0 + x]; }
        #pragma unroll
        for (int x = 0; x < 4; ++x) {
            float col[4];
            #pragma unroll
            for (int y = 0; y < 4; ++y) {
                float e = fmaf(0.4f, aa[y][x], 0.6f * (Pv[y] + Qv[x]));
                const bool allowed = (mi4[y] && mj4[x]) || (i0 + y == j0 + x);
                col[y] = allowed ? e : -1e9f;
            }
            *(float4*)&esT[j0 + x][i0] = *(float4*)col;
        }
    }
    __syncthreads();

    // ---- softmax over j per row i (parallel: thread (q,i) handles 16 j's)
    {
        const int si = tid & 63, q = tid >> 6;
        float mx = -1e30f;
        #pragma unroll
        for (int k = 0; k < 16; ++k) mx = fmaxf(mx, esT[16 * q + k][si]);
        pmax[q][si] = mx;
    }
    __syncthreads();
    if (tid < 64)
        mxf[tid] = fmaxf(fmaxf(pmax[0][tid], pmax[1][tid]),
                         fmaxf(pmax[2][tid], pmax[3][tid]));
    __syncthreads();
    {
        const int si = tid & 63, q = tid >> 6;
        const float mx = mxf[si];
        float s = 0.f;
        #pragma unroll
        for (int k = 0; k < 16; ++k) {
            const float ev = __expf(esT[16 * q + k][si] - mx);
            esT[16 * q + k][si] = ev;
            s += ev;
        }
        psum[q][si] = s;
    }
    __syncthreads();
    if (tid < 64)
        inv[tid] = 1.f / (psum[0][tid] + psum[1][tid] + psum[2][tid] + psum[3][tid]);
    __syncthreads();

    // ---- phase 3: out[i][c] = inv[i] * sum_j w[j][i] * xl[j][c]
    {
        const int c0 = j0;             // reuse 4x4 grid: cols = channels
        float oa[4][4] = {};
        for (int j = 0; j < 64; ++j) {
            float al[4], xv[4];
            *(float4*)al = *(const float4*)&esT[j][i0];
            *(float4*)xv = *(const float4*)&xls[j][c0];
            #pragma unroll
            for (int y = 0; y < 4; ++y)
                #pragma unroll
                for (int x = 0; x < 4; ++x)
                    oa[y][x] = fmaf(al[y], xv[x], oa[y][x]);
        }
        #pragma unroll
        for (int y = 0; y < 4; ++y) {
            const float iv = inv[i0 + y];
            float o[4];
            #pragma unroll
            for (int x = 0; x < 4; ++x) o[x] = oa[y][x] * iv;
            float* go = g + (size_t)(gr * NND + i0 + y) * HID_ + head * NCH + c0;
            *(float4*)go = *(float4*)o;
        }
    }
}

// ---------------------------------------------------------------------------
// g + ob -> ELU -> LayerNorm -> + res -> zero unmasked.
// finalSel=0: always write hout (+ optional bf16 mirror hb).
// finalSel=1: hout = d_out holding h0; only overwrite keep-graphs
// (#masked nodes > 1, via ballot).
__global__ __launch_bounds__(256) void epilogue_kernel(
    const float* __restrict__ g, const float* res,
    const float* __restrict__ ob, const float* __restrict__ lns,
    const float* __restrict__ lnb, const int* __restrict__ msk,
    float* hout, bf16* hb, int finalSel)
{
    const int lane = threadIdx.x & 63;
    const int wave = threadIdx.x >> 6;
    const int m = blockIdx.x * 4 + wave;
    if (finalSel) {
        const int gr = m >> 6;
        const int mv = msk[gr * NND + lane];
        const unsigned long long bal = __ballot(mv != 0);
        if (__popcll(bal) <= 1) return;   // leave h0 rows in d_out
    }
    const float* grow = g + (size_t)m * HID_;
    float v[4];
    float sum = 0.f;
    #pragma unroll
    for (int q = 0; q < 4; ++q) {
        const int c = q * 64 + lane;
        float x = grow[c] + ob[c];
        x = x > 0.f ? x : (__expf(x) - 1.f);   // ELU (alpha=1)
        v[q] = x; sum += x;
    }
    #pragma unroll
    for (int off = 1; off < 64; off <<= 1) sum += __shfl_xor(sum, off);
    const float mu = sum * (1.f / 256.f);
    float vs = 0.f;
    #pragma unroll
    for (int q = 0; q < 4; ++q) { const float d = v[q] - mu; vs += d * d; }
    #pragma unroll
    for (int off = 1; off < 64; off <<= 1) vs += __shfl_xor(vs, off);
    const float rstd = rsqrtf(vs * (1.f / 256.f) + LN_EPS_);
    const int mnode = msk[m];
    const float* rrow = res + (size_t)m * HID_;
    float* ho = hout + (size_t)m * HID_;
    #pragma unroll
    for (int q = 0; q < 4; ++q) {
        const int c = q * 64 + lane;
        float y = (v[q] - mu) * rstd * lns[c] + lnb[c];
        y += rrow[c];
        y = mnode ? y : 0.f;
        ho[c] = y;
        if (hb) hb[(size_t)m * HID_ + c] = __float2bfloat16(y);
    }
}

// ---------------------------------------------------------------------------
extern "C" void kernel_launch(void* const* d_in, const int* in_sizes, int n_in,
                              void* d_out, int out_size, void* d_ws, size_t ws_size,
                              hipStream_t stream) {
    const float* x    = (const float*)d_in[0];
    const float* W_in = (const float*)d_in[2];
    const float* b_in = (const float*)d_in[3];
    const float* Wl   = (const float*)d_in[4];
    const float* bl   = (const float*)d_in[5];
    const float* Wr   = (const float*)d_in[6];
    const float* br   = (const float*)d_in[7];
    const float* att  = (const float*)d_in[8];
    const float* ob   = (const float*)d_in[9];
    const float* lns  = (const float*)d_in[10];
    const float* lnb  = (const float*)d_in[11];
    float* out = (float*)d_out;

    // ws (~29 MB): [mcan 32K][h 8M][xlb 8M][xrb 8M][hxb 4M][WTin 256K][WlrT 512K]
    char* w = (char*)d_ws;
    int*   mcan = (int*)w;                      w += 32768;
    float* h    = (float*)w;                    w += (size_t)NROWS * HID_ * 4;
    float* xlb  = (float*)w;                    w += (size_t)NROWS * HID_ * 4;
    float* xrb  = (float*)w;                    w += (size_t)NROWS * HID_ * 4;
    bf16*  hxb  = (bf16*)w;                     w += (size_t)NROWS * HID_ * 2;
    bf16*  WTin = (bf16*)w;                     w += (size_t)D_IN_ * HID_ * 2;
    bf16*  WlrT = (bf16*)w;                     // [L][512][256]
    float* gb   = xrb;                          // aliased (safe — see attn_kernel)

    transpose_all_kernel<<<dim3(8, 16, 6), 256, 0, stream>>>(
        W_in, Wl, Wr, (const unsigned int*)d_in[1], WTin, WlrT, mcan);

    // d_out <- fp32 h0 = x @ W_in + b_in ; hxb <- bf16(h0)
    gemm_in_kernel<<<dim3(HID_ / 64, NROWS / 64), 256, 0, stream>>>(
        x, WTin, b_in, out, hxb);

    for (int li = 0; li < 2; ++li) {
        const float* resf = (li == 0) ? out : h;   // fp32 residual
        gemm_mfma_kernel<<<dim3(512 / 64, NROWS / 128), 256, 0, stream>>>(
            hxb, WlrT + (size_t)li * 512 * HID_, bl + li * HID_, br + li * HID_,
            xlb, xrb, NROWS, HID_);
        attn_kernel<<<dim3(NH, BT_G), 256, 0, stream>>>(
            xlb, xrb, att + li * NH * NCH, mcan, gb);
        if (li == 0) {
            epilogue_kernel<<<NROWS / 4, 256, 0, stream>>>(
                gb, resf, ob, lns, lnb, mcan, h, hxb, 0);
        } else {
            epilogue_kernel<<<NROWS / 4, 256, 0, stream>>>(
                gb, resf, ob + HID_, lns + HID_, lnb + HID_, mcan,
                out, (bf16*)nullptr, 1);
        }
    }

    (void)in_sizes; (void)n_in; (void)out_size; (void)ws_size;
}